// Round 9
// baseline (336.834 us; speedup 1.0000x reference)
//
#include <hip/hip_runtime.h>
#include <hip/hip_bf16.h>
#include <stdint.h>

// Problem dims (fixed by setup_inputs)
#define M_TOTAL 2048     // B (feats rows)
#define N_TOTAL 16384    // Bs*TOPK (support rows)
#define K_TOTAL 2048     // C
#define NPARTS  128      // 64 n-tiles * 2 n-waves

// Uniform MX scale: stored_fp8 = value * 2^9, HW dequant scale = 2^-9 per operand.
// e8m0 byte = 127 - 9 = 118 = 0x76. Uniform bytes -> immune to scale-lane layout.
#define SCALE_E8M0 0x76767676
#define SCALE_F 512.0f

typedef __attribute__((ext_vector_type(4))) int   int4v;    // 16B (one ds_read_b128)
typedef __attribute__((ext_vector_type(8))) int   int8v;    // 32B fp8 MFMA A/B frag
typedef __attribute__((ext_vector_type(4))) float floatx4;  // MFMA C/D frag

// ---------------------------------------------------------------- fp32 -> fp8 e4m3 (scaled)
__device__ __forceinline__ void cvt_loop(const float4* __restrict__ src,
                                         uint32_t* __restrict__ dst,
                                         int i, int stride, int n4) {
    for (; i < n4; i += stride) {
        float4 v = src[i];
        int p = __builtin_amdgcn_cvt_pk_fp8_f32(v.x * SCALE_F, v.y * SCALE_F, 0, 0);
        p = __builtin_amdgcn_cvt_pk_fp8_f32(v.z * SCALE_F, v.w * SCALE_F, p, 1);
        dst[i] = (uint32_t)p;
    }
}

// one launch for both arrays: blocks [0,512) -> A, [512,2560) -> B (uniform branch)
__global__ void cvt_fp8_all(const float4* __restrict__ a, const float4* __restrict__ b,
                            uint32_t* __restrict__ oa, uint32_t* __restrict__ ob) {
    if (blockIdx.x < 512)
        cvt_loop(a, oa, blockIdx.x * 256 + threadIdx.x, 512 * 256,
                 M_TOTAL * K_TOTAL / 4);
    else
        cvt_loop(b, ob, (blockIdx.x - 512) * 256 + threadIdx.x, 2048 * 256,
                 N_TOTAL * K_TOTAL / 4);
}

// ---------------------------------------------------------------- GEMM + fused epilogue
__device__ __forceinline__ void load16(const void* g, void* l) {
    __builtin_amdgcn_global_load_lds(
        (const __attribute__((address_space(1))) void*)g,
        (__attribute__((address_space(3))) void*)l, 16, 0, 0);
}

// ===== R9: 128x256 block tile, 64x128 wave tile (acc[4][8] = 128 AGPR).
// DIAGNOSIS (R8 counters): the 128^2 kernel is ds_read-THROUGHPUT-bound, not
// MFMA- or sync-bound. Per CU per K-tile period (~1600 cy): matrix pipe needs
// 550 cy (= the pinned 34% MfmaUtil); ds_read_b128 needs 2.2 blk x 4 waves x
// 16 reads x 12 cy ~= 1690 cy — the whole period. That's why all barrier
// re-scheduling variants (R1/R3/R4/R5: 101-132 us) lost: none cut LDS bytes.
// FIX: larger wave output tile cuts ds bytes per FLOP. 64x128/wave: 12 frag
// loads per 2.1 MFLOP = 192 B/MFLOP vs 256 (-25%); staging VALU/FLOP -25%;
// barriers/FLOP -50%. Occupancy unchanged: 128 AGPR + ~90 VGPR <= 256/wave
// keeps 2 waves/SIMD (same 129-256 band as the old 144). K-loop discipline
// (2-barrier, single-buffered, global_load_lds w=16) is byte-identical.
// REJECTED (measured): 256^2 8-wave pipelined family (R1/R3/R4/R5),
// per-row atomics epilogue (R7: 140 us), dbuf single-barrier, BK=256,
// full K-unroll (earlier session).
//
// LDS: A 128x128B (16 KB) + B 256x128B (32 KB), single-buffered. 16B chunk at
// global k-pos q of row R lives at phys q ^ (R&7). Swizzle on the GLOBAL side
// of global_load_lds (LDS dest stays wave-base + lane*16B). Frag reads: two
// ds_read_b128 per 32B operand, 2-way bank aliasing (free per m136).
__global__ __launch_bounds__(256) void gemm_lp(
        const char* __restrict__ Af8, const char* __restrict__ Bf8,
        const int* __restrict__ labels, const int* __restrict__ labels_s,
        float* __restrict__ pminp, float* __restrict__ psump) {
    __shared__ __align__(16) char lsA[128 * 128];   // 16 KB
    __shared__ __align__(16) char lsB[256 * 128];   // 32 KB
    __shared__ int lab_m[128];
    __shared__ int lab_n[256];

    const int t    = threadIdx.x;
    const int lane = t & 63;
    const int wave = t >> 6;
    const int wm   = wave >> 1;   // row half    (0..1): 64 rows each
    const int wn   = wave & 1;    // col half    (0..1): 128 cols each
    const int m0   = blockIdx.y * 128;
    const int n0   = blockIdx.x * 256;

    lab_n[t] = labels_s[n0 + t];
    if (t < 128) lab_m[t] = labels[m0 + t];

    // staging: round j covers rows j*32 + (t>>3); thread t fills phys chunk
    // j*256 + t -> byte j*4096 + t*16. global 16B k-chunk q = (t&7)^((t>>3)&7).
    const int rq = t >> 3;                                  // row within 32-row group
    const int qt = (t & 7) ^ ((t >> 3) & 7);                // swizzled k-chunk
    const char* aPtr = Af8 + (long)(m0 + rq) * K_TOTAL + qt * 16;
    const char* bPtr = Bf8 + (long)(n0 + rq) * K_TOTAL + qt * 16;
    char* lA = lsA + wave * 1024;            // wave-uniform LDS base; HW adds lane*16B
    char* lB = lsB + wave * 1024;

    // Fragment bases: A row = wm*64 + lcol (+ mi*16), B row = wn*128 + lcol
    // (+ ni*16); k-chunks {2q,2q+1} at phys (k ^ (lcol&7)); row steps fold
    // into ds_read 16-bit immediates (max 7*2048+plo < 16 KB within lsB).
    const int quad = lane >> 4;
    const int lcol = lane & 15;
    const int plo = ((2 * quad) ^ (lcol & 7)) << 4;
    const int phi = ((2 * quad + 1) ^ (lcol & 7)) << 4;
    const char* aLo = lsA + (wm * 64 + lcol) * 128 + plo;
    const char* aHi = lsA + (wm * 64 + lcol) * 128 + phi;
    const char* bLo = lsB + (wn * 128 + lcol) * 128 + plo;
    const char* bHi = lsB + (wn * 128 + lcol) * 128 + phi;

    floatx4 acc[4][8];                       // 128 AGPRs
#pragma unroll
    for (int mi = 0; mi < 4; ++mi)
#pragma unroll
        for (int ni = 0; ni < 8; ++ni)
            acc[mi][ni] = (floatx4){0.f, 0.f, 0.f, 0.f};

#pragma unroll 1
    for (int kt = 0; kt < K_TOTAL / 128; ++kt) {            // 16 iterations, NOT unrolled
        __syncthreads();                         // previous iter's frag reads done
#pragma unroll
        for (int j = 0; j < 4; ++j)
            load16(aPtr + j * 32 * K_TOTAL, lA + j * 4096);
#pragma unroll
        for (int j = 0; j < 8; ++j)
            load16(bPtr + j * 32 * K_TOTAL, lB + j * 4096);
        aPtr += 128;
        bPtr += 128;
        __syncthreads();                         // drains vmcnt -> tiles ready

        // Hold all 4 A-frags (32 VGPRs); stream B-frags one at a time.
        int8v av[4];
#pragma unroll
        for (int mi = 0; mi < 4; ++mi) {
            int4v lo = *(const int4v*)(aLo + mi * 2048);
            int4v hi = *(const int4v*)(aHi + mi * 2048);
            av[mi] = (int8v){lo.x, lo.y, lo.z, lo.w, hi.x, hi.y, hi.z, hi.w};
        }
#pragma unroll
        for (int ni = 0; ni < 8; ++ni) {
            int4v lo = *(const int4v*)(bLo + ni * 2048);
            int4v hi = *(const int4v*)(bHi + ni * 2048);
            int8v bvv = (int8v){lo.x, lo.y, lo.z, lo.w, hi.x, hi.y, hi.z, hi.w};
#pragma unroll
            for (int mi = 0; mi < 4; ++mi)
                acc[mi][ni] = __builtin_amdgcn_mfma_scale_f32_16x16x128_f8f6f4(
                    av[mi], bvv, acc[mi][ni],
                    0, 0,                         // cbsz=fp8(e4m3), blgp=fp8(e4m3)
                    0, SCALE_E8M0,                // opsel_a, scale_a (2^-9 all bytes)
                    0, SCALE_E8M0);               // opsel_b, scale_b
        }
    }

    // Epilogue: e = exp(sim/TEMP) = exp2(sim * 28.8539); masked min/sum over cols.
    // C/D layout (shape-determined): col = lane&15, row = quad*4 + reg
    const float scale = 28.853900817779268f;     // 20 * log2(e)
#pragma unroll
    for (int mi = 0; mi < 4; ++mi) {
#pragma unroll
        for (int r = 0; r < 4; ++r) {
            const int row_local = wm * 64 + mi * 16 + quad * 4 + r;
            const int lab = lab_m[row_local];
            float minv = __builtin_inff();
            float sumv = 0.f;
#pragma unroll
            for (int ni = 0; ni < 8; ++ni) {
                const int col_local = wn * 128 + ni * 16 + lcol;
                const float e = exp2f(acc[mi][ni][r] * scale);
                const bool pos = (lab_n[col_local] == lab);
                minv = pos ? fminf(minv, e) : minv;
                sumv = pos ? sumv : (sumv + e);
            }
#pragma unroll
            for (int off = 1; off < 16; off <<= 1) {
                minv = fminf(minv, __shfl_xor(minv, off, 16));
                sumv += __shfl_xor(sumv, off, 16);
            }
            if (lcol == 0) {
                // partials laid out [row][part] so reduce_rows reads coalesced
                const long idx = (long)(m0 + row_local) * NPARTS + blockIdx.x * 2 + wn;
                pminp[idx] = minv;
                psump[idx] = sumv;
            }
        }
    }
}

// ---------------------------------------------------------------- row fold + mean
// one wave per row, 512 blocks x 4 waves = 2048 waves
__global__ __launch_bounds__(256) void reduce_rows(
        const float* __restrict__ pminp, const float* __restrict__ psump,
        float* __restrict__ loss) {
    const int row  = blockIdx.x * 4 + (threadIdx.x >> 6);
    const int lane = threadIdx.x & 63;
    float m = __builtin_inff();
    float s = 0.f;
#pragma unroll
    for (int k = 0; k < NPARTS / 64; ++k) {
        const long j = (long)row * NPARTS + lane + k * 64;
        m = fminf(m, pminp[j]);
        s += psump[j];
    }
#pragma unroll
    for (int off = 1; off < 64; off <<= 1) {
        m = fminf(m, __shfl_xor(m, off, 64));
        s += __shfl_xor(s, off, 64);
    }
    if (lane == 0) loss[row] = -logf(m / (m + s + 1e-6f) + 1e-6f);
}

__global__ void final_mean(const float* __restrict__ loss, float* __restrict__ out) {
    float s = 0.f;
    for (int i = threadIdx.x; i < M_TOTAL; i += 256) s += loss[i];
#pragma unroll
    for (int off = 32; off > 0; off >>= 1) s += __shfl_xor(s, off, 64);
    __shared__ float wsum[4];
    if ((threadIdx.x & 63) == 0) wsum[threadIdx.x >> 6] = s;
    __syncthreads();
    if (threadIdx.x == 0)
        out[0] = (wsum[0] + wsum[1] + wsum[2] + wsum[3]) * (1.0f / (float)M_TOTAL);
}

// ---------------------------------------------------------------- launcher
extern "C" void kernel_launch(void* const* d_in, const int* in_sizes, int n_in,
                              void* d_out, int out_size, void* d_ws, size_t ws_size,
                              hipStream_t stream) {
    const float* feats    = (const float*)d_in[0];
    const float* feats_s  = (const float*)d_in[1];
    const int*   labels   = (const int*)d_in[2];
    const int*   labels_s = (const int*)d_in[3];
    float*       out      = (float*)d_out;

    char* ws = (char*)d_ws;
    char*  Af8   = ws;                                    //  4,194,304 B
    char*  Bf8   = ws + 4194304;                          // 33,554,432 B
    float* pminp = (float*)(ws + 37748736);               //  1,048,576 B
    float* psump = (float*)(ws + 39845888);               //  1,048,576 B
    float* loss  = (float*)(ws + 41943040);               //      8,192 B

    cvt_fp8_all<<<2560, 256, 0, stream>>>((const float4*)feats, (const float4*)feats_s,
                                          (uint32_t*)Af8, (uint32_t*)Bf8);

    dim3 grid(N_TOTAL / 256, M_TOTAL / 128);              // 64 x 16
    gemm_lp<<<grid, 256, 0, stream>>>(Af8, Bf8, labels, labels_s, pminp, psump);

    reduce_rows<<<512, 256, 0, stream>>>(pminp, psump, loss);
    final_mean<<<1, 256, 0, stream>>>(loss, out);
}

// Round 10
// 283.682 us; speedup vs baseline: 1.1874x; 1.1874x over previous
//
#include <hip/hip_runtime.h>
#include <hip/hip_bf16.h>
#include <stdint.h>

// Problem dims (fixed by setup_inputs)
#define M_TOTAL 2048     // B (feats rows)
#define N_TOTAL 16384    // Bs*TOPK (support rows)
#define K_TOTAL 2048     // C
#define NPARTS  128      // 64 n-tiles * 2 n-waves

// Uniform MX scale: stored_fp8 = value * 2^9, HW dequant scale = 2^-9 per operand.
// e8m0 byte = 127 - 9 = 118 = 0x76. Uniform bytes -> immune to scale-lane layout.
#define SCALE_E8M0 0x76767676
#define SCALE_F 512.0f

typedef __attribute__((ext_vector_type(4))) int   int4v;    // 16B (one ds_read_b128)
typedef __attribute__((ext_vector_type(8))) int   int8v;    // 32B fp8 MFMA A/B frag
typedef __attribute__((ext_vector_type(4))) float floatx4;  // MFMA C/D frag

// ---------------------------------------------------------------- fp32 -> fp8 e4m3 (scaled)
__device__ __forceinline__ void cvt_loop(const float4* __restrict__ src,
                                         uint32_t* __restrict__ dst,
                                         int i, int stride, int n4) {
    for (; i < n4; i += stride) {
        float4 v = src[i];
        int p = __builtin_amdgcn_cvt_pk_fp8_f32(v.x * SCALE_F, v.y * SCALE_F, 0, 0);
        p = __builtin_amdgcn_cvt_pk_fp8_f32(v.z * SCALE_F, v.w * SCALE_F, p, 1);
        dst[i] = (uint32_t)p;
    }
}

// one launch for both arrays: blocks [0,512) -> A, [512,2560) -> B (uniform branch)
__global__ void cvt_fp8_all(const float4* __restrict__ a, const float4* __restrict__ b,
                            uint32_t* __restrict__ oa, uint32_t* __restrict__ ob) {
    if (blockIdx.x < 512)
        cvt_loop(a, oa, blockIdx.x * 256 + threadIdx.x, 512 * 256,
                 M_TOTAL * K_TOTAL / 4);
    else
        cvt_loop(b, ob, (blockIdx.x - 512) * 256 + threadIdx.x, 2048 * 256,
                 N_TOTAL * K_TOTAL / 4);
}

// ---------------------------------------------------------------- GEMM + fused epilogue
__device__ __forceinline__ void load16(const void* g, void* l) {
    __builtin_amdgcn_global_load_lds(
        (const __attribute__((address_space(1))) void*)g,
        (__attribute__((address_space(3))) void*)l, 16, 0, 0);
}

// ===== R10: 128x256 block / 64x128 wave tile (acc[4][8] = 128 AGPR), with the
// R9 occupancy cliff fixed.
// R9 POST-MORTEM: VGPR 144 + 128 AGPR = 272 > 256 unified -> 1 wave/SIMD
// (occupancy 11.6%), zero latency hiding, MfmaUtil 16%, gemm 168 us. The
// ds_read-bound theory (R8 counters: ds demand ~1690 cy/tile-period vs MFMA
// 550 cy -> 34% pinned MfmaUtil) was NEVER TESTED — confounded by occupancy.
// FIXES (only two changes vs R9):
//   1. __launch_bounds__(256, 2): forces combined <=256/wave -> 2 waves/SIMD.
//   2. staging addresses as #pragma unroll 1 pointer-increment loops (1 live
//      address pair instead of 12 unrolled ones) — removes the arch-VGPR fat
//      so the forced cap spills ~nothing. WATCH WRITE_SIZE: >30 MB = spill =
//      dead (R3 lesson), regardless of timing.
// Tile math unchanged: 12 frag loads / 2.1 MFLOP = 183 B/MFLOP vs R8's 244
// (-25% ds bytes/FLOP); barriers/FLOP -50%.
// REJECTED (measured): 256^2 8-wave pipelined family (R1/R3/R4/R5: 101-168us),
// per-row atomics epilogue (R7: 140 us), dbuf single-barrier, BK=256,
// full K-unroll (earlier session).
//
// LDS: A 128x128B (16 KB) + B 256x128B (32 KB), single-buffered. 16B chunk at
// global k-pos q of row R lives at phys q ^ (R&7). Swizzle on the GLOBAL side
// of global_load_lds (LDS dest stays wave-base + lane*16B). Frag reads: two
// ds_read_b128 per 32B operand, 2-way bank aliasing (free per m136).
__global__ __launch_bounds__(256, 2) void gemm_lp(
        const char* __restrict__ Af8, const char* __restrict__ Bf8,
        const int* __restrict__ labels, const int* __restrict__ labels_s,
        float* __restrict__ pminp, float* __restrict__ psump) {
    __shared__ __align__(16) char lsA[128 * 128];   // 16 KB
    __shared__ __align__(16) char lsB[256 * 128];   // 32 KB
    __shared__ int lab_m[128];
    __shared__ int lab_n[256];

    const int t    = threadIdx.x;
    const int lane = t & 63;
    const int wave = t >> 6;
    const int wm   = wave >> 1;   // row half    (0..1): 64 rows each
    const int wn   = wave & 1;    // col half    (0..1): 128 cols each
    const int m0   = blockIdx.y * 128;
    const int n0   = blockIdx.x * 256;

    lab_n[t] = labels_s[n0 + t];
    if (t < 128) lab_m[t] = labels[m0 + t];

    // staging: round j covers rows j*32 + (t>>3); thread t fills phys chunk
    // j*256 + t -> byte j*4096 + t*16. global 16B k-chunk q = (t&7)^((t>>3)&7).
    const int rq = t >> 3;                                  // row within 32-row group
    const int qt = (t & 7) ^ ((t >> 3) & 7);                // swizzled k-chunk
    const char* aPtr = Af8 + (long)(m0 + rq) * K_TOTAL + qt * 16;
    const char* bPtr = Bf8 + (long)(n0 + rq) * K_TOTAL + qt * 16;
    char* lA = lsA + wave * 1024;            // wave-uniform LDS base; HW adds lane*16B
    char* lB = lsB + wave * 1024;

    // Fragment bases: A row = wm*64 + lcol (+ mi*16), B row = wn*128 + lcol
    // (+ ni*16); k-chunks {2q,2q+1} at phys (k ^ (lcol&7)); row steps fold
    // into ds_read 16-bit immediates (max 7*2048+plo < 16 KB within lsB).
    const int quad = lane >> 4;
    const int lcol = lane & 15;
    const int plo = ((2 * quad) ^ (lcol & 7)) << 4;
    const int phi = ((2 * quad + 1) ^ (lcol & 7)) << 4;
    const char* aLo = lsA + (wm * 64 + lcol) * 128 + plo;
    const char* aHi = lsA + (wm * 64 + lcol) * 128 + phi;
    const char* bLo = lsB + (wn * 128 + lcol) * 128 + plo;
    const char* bHi = lsB + (wn * 128 + lcol) * 128 + phi;

    floatx4 acc[4][8];                       // 128 AGPRs
#pragma unroll
    for (int mi = 0; mi < 4; ++mi)
#pragma unroll
        for (int ni = 0; ni < 8; ++ni)
            acc[mi][ni] = (floatx4){0.f, 0.f, 0.f, 0.f};

#pragma unroll 1
    for (int kt = 0; kt < K_TOTAL / 128; ++kt) {            // 16 iterations, NOT unrolled
        __syncthreads();                         // previous iter's frag reads done
        {   // pointer-increment staging: ONE live address pair per loop
            const char* ap = aPtr;
            char* la = lA;
#pragma unroll 1
            for (int j = 0; j < 4; ++j) {
                load16(ap, la);
                ap += 32 * K_TOTAL;
                la += 4096;
            }
            const char* bp = bPtr;
            char* lb = lB;
#pragma unroll 1
            for (int j = 0; j < 8; ++j) {
                load16(bp, lb);
                bp += 32 * K_TOTAL;
                lb += 4096;
            }
        }
        aPtr += 128;
        bPtr += 128;
        __syncthreads();                         // drains vmcnt -> tiles ready

        // Hold all 4 A-frags (32 VGPRs); stream B-frags one at a time.
        int8v av[4];
#pragma unroll
        for (int mi = 0; mi < 4; ++mi) {
            int4v lo = *(const int4v*)(aLo + mi * 2048);
            int4v hi = *(const int4v*)(aHi + mi * 2048);
            av[mi] = (int8v){lo.x, lo.y, lo.z, lo.w, hi.x, hi.y, hi.z, hi.w};
        }
#pragma unroll
        for (int ni = 0; ni < 8; ++ni) {
            int4v lo = *(const int4v*)(bLo + ni * 2048);
            int4v hi = *(const int4v*)(bHi + ni * 2048);
            int8v bvv = (int8v){lo.x, lo.y, lo.z, lo.w, hi.x, hi.y, hi.z, hi.w};
#pragma unroll
            for (int mi = 0; mi < 4; ++mi)
                acc[mi][ni] = __builtin_amdgcn_mfma_scale_f32_16x16x128_f8f6f4(
                    av[mi], bvv, acc[mi][ni],
                    0, 0,                         // cbsz=fp8(e4m3), blgp=fp8(e4m3)
                    0, SCALE_E8M0,                // opsel_a, scale_a (2^-9 all bytes)
                    0, SCALE_E8M0);               // opsel_b, scale_b
        }
    }

    // Epilogue: e = exp(sim/TEMP) = exp2(sim * 28.8539); masked min/sum over cols.
    // C/D layout (shape-determined): col = lane&15, row = quad*4 + reg
    const float scale = 28.853900817779268f;     // 20 * log2(e)
#pragma unroll
    for (int mi = 0; mi < 4; ++mi) {
#pragma unroll
        for (int r = 0; r < 4; ++r) {
            const int row_local = wm * 64 + mi * 16 + quad * 4 + r;
            const int lab = lab_m[row_local];
            float minv = __builtin_inff();
            float sumv = 0.f;
#pragma unroll
            for (int ni = 0; ni < 8; ++ni) {
                const int col_local = wn * 128 + ni * 16 + lcol;
                const float e = exp2f(acc[mi][ni][r] * scale);
                const bool pos = (lab_n[col_local] == lab);
                minv = pos ? fminf(minv, e) : minv;
                sumv = pos ? sumv : (sumv + e);
            }
#pragma unroll
            for (int off = 1; off < 16; off <<= 1) {
                minv = fminf(minv, __shfl_xor(minv, off, 16));
                sumv += __shfl_xor(sumv, off, 16);
            }
            if (lcol == 0) {
                // partials laid out [row][part] so reduce_rows reads coalesced
                const long idx = (long)(m0 + row_local) * NPARTS + blockIdx.x * 2 + wn;
                pminp[idx] = minv;
                psump[idx] = sumv;
            }
        }
    }
}

// ---------------------------------------------------------------- row fold + mean
// one wave per row, 512 blocks x 4 waves = 2048 waves
__global__ __launch_bounds__(256) void reduce_rows(
        const float* __restrict__ pminp, const float* __restrict__ psump,
        float* __restrict__ loss) {
    const int row  = blockIdx.x * 4 + (threadIdx.x >> 6);
    const int lane = threadIdx.x & 63;
    float m = __builtin_inff();
    float s = 0.f;
#pragma unroll
    for (int k = 0; k < NPARTS / 64; ++k) {
        const long j = (long)row * NPARTS + lane + k * 64;
        m = fminf(m, pminp[j]);
        s += psump[j];
    }
#pragma unroll
    for (int off = 1; off < 64; off <<= 1) {
        m = fminf(m, __shfl_xor(m, off, 64));
        s += __shfl_xor(s, off, 64);
    }
    if (lane == 0) loss[row] = -logf(m / (m + s + 1e-6f) + 1e-6f);
}

__global__ void final_mean(const float* __restrict__ loss, float* __restrict__ out) {
    float s = 0.f;
    for (int i = threadIdx.x; i < M_TOTAL; i += 256) s += loss[i];
#pragma unroll
    for (int off = 32; off > 0; off >>= 1) s += __shfl_xor(s, off, 64);
    __shared__ float wsum[4];
    if ((threadIdx.x & 63) == 0) wsum[threadIdx.x >> 6] = s;
    __syncthreads();
    if (threadIdx.x == 0)
        out[0] = (wsum[0] + wsum[1] + wsum[2] + wsum[3]) * (1.0f / (float)M_TOTAL);
}

// ---------------------------------------------------------------- launcher
extern "C" void kernel_launch(void* const* d_in, const int* in_sizes, int n_in,
                              void* d_out, int out_size, void* d_ws, size_t ws_size,
                              hipStream_t stream) {
    const float* feats    = (const float*)d_in[0];
    const float* feats_s  = (const float*)d_in[1];
    const int*   labels   = (const int*)d_in[2];
    const int*   labels_s = (const int*)d_in[3];
    float*       out      = (float*)d_out;

    char* ws = (char*)d_ws;
    char*  Af8   = ws;                                    //  4,194,304 B
    char*  Bf8   = ws + 4194304;                          // 33,554,432 B
    float* pminp = (float*)(ws + 37748736);               //  1,048,576 B
    float* psump = (float*)(ws + 39845888);               //  1,048,576 B
    float* loss  = (float*)(ws + 41943040);               //      8,192 B

    cvt_fp8_all<<<2560, 256, 0, stream>>>((const float4*)feats, (const float4*)feats_s,
                                          (uint32_t*)Af8, (uint32_t*)Bf8);

    dim3 grid(N_TOTAL / 256, M_TOTAL / 128);              // 64 x 16
    gemm_lp<<<grid, 256, 0, stream>>>(Af8, Bf8, labels, labels_s, pminp, psump);

    reduce_rows<<<512, 256, 0, stream>>>(pminp, psump, loss);
    final_mean<<<1, 256, 0, stream>>>(loss, out);
}